// Round 10
// baseline (292.149 us; speedup 1.0000x reference)
//
#include <hip/hip_runtime.h>
#include <hip/hip_fp16.h>

#define FIN 128
#define HID 32
#define BSHIFT 8                 // 256 nodes per coarse bucket
#define BNODES 256
#define CHUNK 2048               // edges per chunk-sort block
#define NBMAX 512                // max coarse buckets supported in LDS
#define CAPB 8960                // max entries per bucket (mean 8184, +8.6 sigma)
#define G1ROWS 64                // rows per gemm block
#define XPAD 4                   // LDS leading-dim pad (keeps 16-B alignment, breaks pow-2 stride)

// ---------------- A: per-chunk counting sort by bucket (all I/O coalesced) ----------------

__global__ __launch_bounds__(256) void chunk_sort_kernel(const int* __restrict__ src,
                                                         const int* __restrict__ dst,
                                                         int* __restrict__ ec,
                                                         unsigned short* __restrict__ offt,
                                                         int E, int nb) {
    __shared__ int hist[NBMAX];
    __shared__ int pref[NBMAX];
    __shared__ int wsum[128];
    __shared__ int sorted[CHUNK];
    int c = blockIdx.x, t = threadIdx.x;
    int beg = c * CHUNK;
    int cnt = min(CHUNK, E - beg);
    for (int i = t; i < nb; i += 256) hist[i] = 0;
    __syncthreads();
    int bk[8], ent[8];
    #pragma unroll
    for (int j = 0; j < 8; ++j) {
        int i = t + j * 256;
        if (i < cnt) {
            int d = dst[beg + i];
            bk[j]  = ((unsigned)d) >> BSHIFT;
            ent[j] = src[beg + i] | ((d & (BNODES - 1)) << 24);
            atomicAdd(&hist[bk[j]], 1);
        } else bk[j] = -1;
    }
    __syncthreads();
    if (t < 128) {
        int s = 0;
        #pragma unroll
        for (int j = 0; j < 4; ++j) {
            int idx = t * 4 + j;
            int v = (idx < nb) ? hist[idx] : 0;
            pref[idx] = s; s += v;
        }
        wsum[t] = s;
    }
    __syncthreads();
    if (t == 0) { int run = 0; for (int j = 0; j < 128; ++j) { int v = wsum[j]; wsum[j] = run; run += v; } }
    __syncthreads();
    for (int i = t; i < nb; i += 256) { int p = pref[i] + wsum[i >> 2]; pref[i] = p; hist[i] = p; }
    __syncthreads();
    #pragma unroll
    for (int j = 0; j < 8; ++j) {
        if (bk[j] >= 0) {
            int p = atomicAdd(&hist[bk[j]], 1);
            sorted[p] = ent[j];
        }
    }
    __syncthreads();
    for (int i = t; i < cnt; i += 256) ec[(size_t)c * CHUNK + i] = sorted[i];   // coalesced
    unsigned short* row = offt + (size_t)c * (nb + 1);
    for (int i = t; i < nb; i += 256) row[i] = (unsigned short)pref[i];
    if (t == 0) row[nb] = (unsigned short)cnt;
}

// ---------------- B: per-bucket gather of chunk runs + node counting sort ----------------

__global__ __launch_bounds__(1024) void bucket_build_kernel(const int* __restrict__ ec,
                                                            const unsigned short* __restrict__ offt,
                                                            int* __restrict__ entries,
                                                            float* __restrict__ dinv,
                                                            int* __restrict__ rowbeg,
                                                            int* __restrict__ rowcnt,
                                                            int n, int nb, int nchunks, int cap) {
    __shared__ int raw[CAPB];
    __shared__ int srt[CAPB];
    __shared__ int hist[BNODES];
    __shared__ int pref[BNODES];
    __shared__ int cursor[BNODES];
    __shared__ int wsum[64];
    __shared__ int nfill;
    int b = blockIdx.x, t = threadIdx.x;
    if (t < BNODES) hist[t] = 0;
    if (t == 0) nfill = 0;
    __syncthreads();
    for (int c = t; c < nchunks; c += 1024) {
        const unsigned short* row = offt + (size_t)c * (nb + 1);
        int s = row[b], e2 = row[b + 1];
        int m = e2 - s;
        if (m > 0) {
            int base = atomicAdd(&nfill, m);
            const int* p = ec + (size_t)c * CHUNK + s;
            for (int k = 0; k < m; ++k) {
                int e = p[k];
                if (base + k < CAPB) raw[base + k] = e;
                atomicAdd(&hist[((unsigned)e) >> 24], 1);
            }
        }
    }
    __syncthreads();
    int total = min(nfill, CAPB);
    if (t < 64) {
        int s = 0;
        #pragma unroll
        for (int j = 0; j < 4; ++j) { int v = hist[t * 4 + j]; pref[t * 4 + j] = s; s += v; }
        wsum[t] = s;
    }
    __syncthreads();
    if (t == 0) { int run = 0; for (int j = 0; j < 64; ++j) { int v = wsum[j]; wsum[j] = run; run += v; } }
    __syncthreads();
    if (t < BNODES) { int p = pref[t] + wsum[t >> 2]; pref[t] = p; cursor[t] = p; }
    __syncthreads();
    for (int i = t; i < total; i += 1024) {
        int e = raw[i];
        int p = atomicAdd(&cursor[((unsigned)e) >> 24], 1);
        srt[p] = e;
    }
    __syncthreads();
    int* ep = entries + (size_t)b * cap;
    for (int i = t; i < total; i += 1024) ep[i] = srt[i];
    int node = b * BNODES + t;
    if (t < BNODES && node < n) {
        int deg = hist[t];
        dinv[node]   = rsqrtf((float)deg + 1.0f);   // +1 = self-loop
        rowbeg[node] = b * cap + pref[t];
        rowcnt[node] = deg;
    }
}

// ---------------- GEMM1: h16 = (x @ W1) * dinv, register-tiled 2x4, K=128 ----------------

__global__ __launch_bounds__(256) void gemm1_kernel(const float* __restrict__ x,
                                                    const float* __restrict__ W,
                                                    const float* __restrict__ dinv,
                                                    __half* __restrict__ h16, int n) {
    __shared__ float Ws[FIN * HID];              // 16 KB
    __shared__ float xs[G1ROWS][FIN + XPAD];     // 33.8 KB
    int t = threadIdx.x;
    for (int i = t; i < FIN * HID; i += 256) Ws[i] = W[i];
    int row0 = blockIdx.x * G1ROWS;
    for (int idx = t; idx < G1ROWS * (FIN / 4); idx += 256) {
        int r  = idx >> 5;
        int c4 = (idx & 31) * 4;
        int row = row0 + r;
        float4 v = (row < n) ? *(const float4*)&x[(size_t)row * FIN + c4]
                             : make_float4(0.f, 0.f, 0.f, 0.f);
        *(float4*)&xs[r][c4] = v;
    }
    __syncthreads();
    int tr = t >> 3, tc = t & 7;
    int r0 = tr * 2, c0 = tc * 4;
    float4 a0 = make_float4(0.f, 0.f, 0.f, 0.f);
    float4 a1 = make_float4(0.f, 0.f, 0.f, 0.f);
    #pragma unroll 8
    for (int k4 = 0; k4 < FIN / 4; ++k4) {
        float4 xv0 = *(const float4*)&xs[r0][k4 * 4];
        float4 xv1 = *(const float4*)&xs[r0 + 1][k4 * 4];
        float4 w0 = *(const float4*)&Ws[(k4 * 4 + 0) * HID + c0];
        float4 w1 = *(const float4*)&Ws[(k4 * 4 + 1) * HID + c0];
        float4 w2 = *(const float4*)&Ws[(k4 * 4 + 2) * HID + c0];
        float4 w3 = *(const float4*)&Ws[(k4 * 4 + 3) * HID + c0];
        a0.x = fmaf(xv0.x, w0.x, a0.x); a0.y = fmaf(xv0.x, w0.y, a0.y);
        a0.z = fmaf(xv0.x, w0.z, a0.z); a0.w = fmaf(xv0.x, w0.w, a0.w);
        a0.x = fmaf(xv0.y, w1.x, a0.x); a0.y = fmaf(xv0.y, w1.y, a0.y);
        a0.z = fmaf(xv0.y, w1.z, a0.z); a0.w = fmaf(xv0.y, w1.w, a0.w);
        a0.x = fmaf(xv0.z, w2.x, a0.x); a0.y = fmaf(xv0.z, w2.y, a0.y);
        a0.z = fmaf(xv0.z, w2.z, a0.z); a0.w = fmaf(xv0.z, w2.w, a0.w);
        a0.x = fmaf(xv0.w, w3.x, a0.x); a0.y = fmaf(xv0.w, w3.y, a0.y);
        a0.z = fmaf(xv0.w, w3.z, a0.z); a0.w = fmaf(xv0.w, w3.w, a0.w);
        a1.x = fmaf(xv1.x, w0.x, a1.x); a1.y = fmaf(xv1.x, w0.y, a1.y);
        a1.z = fmaf(xv1.x, w0.z, a1.z); a1.w = fmaf(xv1.x, w0.w, a1.w);
        a1.x = fmaf(xv1.y, w1.x, a1.x); a1.y = fmaf(xv1.y, w1.y, a1.y);
        a1.z = fmaf(xv1.y, w1.z, a1.z); a1.w = fmaf(xv1.y, w1.w, a1.w);
        a1.x = fmaf(xv1.z, w2.x, a1.x); a1.y = fmaf(xv1.z, w2.y, a1.y);
        a1.z = fmaf(xv1.z, w2.z, a1.z); a1.w = fmaf(xv1.z, w2.w, a1.w);
        a1.x = fmaf(xv1.w, w3.x, a1.x); a1.y = fmaf(xv1.w, w3.y, a1.y);
        a1.z = fmaf(xv1.w, w3.z, a1.z); a1.w = fmaf(xv1.w, w3.w, a1.w);
    }
    #pragma unroll
    for (int rr = 0; rr < 2; ++rr) {
        int row = row0 + r0 + rr;
        float4 a = rr ? a1 : a0;
        float sc = (row < n) ? dinv[row] : 0.f;
        __half2 p0 = __floats2half2_rn(a.x * sc, a.y * sc);
        __half2 p1 = __floats2half2_rn(a.z * sc, a.w * sc);
        __half2* dst = (__half2*)&h16[(size_t)row * HID + c0];
        dst[0] = p0;
        dst[1] = p1;
    }
}

// ---------------- gather: 4 lanes per node, dwordx4 row loads, no shfl ----------------
// out[i] = relu( b + di * (h16[i] + sum_e h16[src]) ); lane q owns feats q*8..q*8+7.

__global__ __launch_bounds__(256) void gather_kernel(const int* __restrict__ entries,
                                                     const int* __restrict__ rowbeg,
                                                     const int* __restrict__ rowcnt,
                                                     const float* __restrict__ dinv,
                                                     const __half* __restrict__ h16,
                                                     const float* __restrict__ bias,
                                                     float* __restrict__ out, int n, int sent) {
    int t = threadIdx.x;
    int g = t >> 2, q = t & 3;
    int i = blockIdx.x * 64 + g;
    if (i >= n) return;
    float di = dinv[i];
    float s0, s1, s2, s3, s4, s5, s6, s7;
    {   // self term: h*di^2 = h16*di
        float4 raw = *(const float4*)&h16[(size_t)i * HID + q * 8];
        __half2 h0 = *(__half2*)&raw.x, h1 = *(__half2*)&raw.y;
        __half2 h2 = *(__half2*)&raw.z, h3 = *(__half2*)&raw.w;
        float2 f0 = __half22float2(h0), f1 = __half22float2(h1);
        float2 f2 = __half22float2(h2), f3 = __half22float2(h3);
        s0 = f0.x; s1 = f0.y; s2 = f1.x; s3 = f1.y;
        s4 = f2.x; s5 = f2.y; s6 = f3.x; s7 = f3.y;
    }
    int beg = rowbeg[i], cnt = rowcnt[i];
    for (int base = 0; base < cnt; base += 4) {
        int e[4];
        #pragma unroll
        for (int u = 0; u < 4; ++u)
            e[u] = (base + u < cnt) ? (entries[beg + base + u] & 0xFFFFFF) : sent;
        float4 raw[4];
        #pragma unroll
        for (int u = 0; u < 4; ++u)
            raw[u] = *(const float4*)&h16[(size_t)e[u] * HID + q * 8];  // 4 x 16B in flight
        #pragma unroll
        for (int u = 0; u < 4; ++u) {
            __half2 h0 = *(__half2*)&raw[u].x, h1 = *(__half2*)&raw[u].y;
            __half2 h2 = *(__half2*)&raw[u].z, h3 = *(__half2*)&raw[u].w;
            float2 f0 = __half22float2(h0), f1 = __half22float2(h1);
            float2 f2 = __half22float2(h2), f3 = __half22float2(h3);
            s0 += f0.x; s1 += f0.y; s2 += f1.x; s3 += f1.y;
            s4 += f2.x; s5 += f2.y; s6 += f3.x; s7 += f3.y;
        }
    }
    float4 b0 = *(const float4*)&bias[q * 8];
    float4 b1 = *(const float4*)&bias[q * 8 + 4];
    float4 o0, o1;
    o0.x = fmaxf(b0.x + di * s0, 0.f); o0.y = fmaxf(b0.y + di * s1, 0.f);
    o0.z = fmaxf(b0.z + di * s2, 0.f); o0.w = fmaxf(b0.w + di * s3, 0.f);
    o1.x = fmaxf(b1.x + di * s4, 0.f); o1.y = fmaxf(b1.y + di * s5, 0.f);
    o1.z = fmaxf(b1.z + di * s6, 0.f); o1.w = fmaxf(b1.w + di * s7, 0.f);
    float* op = &out[(size_t)i * HID + q * 8];
    *(float4*)op = o0;
    *(float4*)(op + 4) = o1;
}

// ---------------- GEMM2: h16 = (hin @ W2) * dinv, register-tiled 2x4, K=32 ----------------

__global__ __launch_bounds__(256) void gemm2_kernel(const float* __restrict__ hin,
                                                    const float* __restrict__ W,
                                                    const float* __restrict__ dinv,
                                                    __half* __restrict__ h16, int n) {
    __shared__ float Ws[HID * HID];              // 4 KB
    __shared__ float hs[G1ROWS][HID + XPAD];     // 9 KB
    int t = threadIdx.x;
    for (int i = t; i < HID * HID; i += 256) Ws[i] = W[i];
    int row0 = blockIdx.x * G1ROWS;
    for (int idx = t; idx < G1ROWS * (HID / 4); idx += 256) {
        int r  = idx >> 3;
        int c4 = (idx & 7) * 4;
        int row = row0 + r;
        float4 v = (row < n) ? *(const float4*)&hin[(size_t)row * HID + c4]
                             : make_float4(0.f, 0.f, 0.f, 0.f);
        *(float4*)&hs[r][c4] = v;
    }
    __syncthreads();
    int tr = t >> 3, tc = t & 7;
    int r0 = tr * 2, c0 = tc * 4;
    float4 a0 = make_float4(0.f, 0.f, 0.f, 0.f);
    float4 a1 = make_float4(0.f, 0.f, 0.f, 0.f);
    #pragma unroll
    for (int k4 = 0; k4 < HID / 4; ++k4) {
        float4 xv0 = *(const float4*)&hs[r0][k4 * 4];
        float4 xv1 = *(const float4*)&hs[r0 + 1][k4 * 4];
        float4 w0 = *(const float4*)&Ws[(k4 * 4 + 0) * HID + c0];
        float4 w1 = *(const float4*)&Ws[(k4 * 4 + 1) * HID + c0];
        float4 w2 = *(const float4*)&Ws[(k4 * 4 + 2) * HID + c0];
        float4 w3 = *(const float4*)&Ws[(k4 * 4 + 3) * HID + c0];
        a0.x = fmaf(xv0.x, w0.x, a0.x); a0.y = fmaf(xv0.x, w0.y, a0.y);
        a0.z = fmaf(xv0.x, w0.z, a0.z); a0.w = fmaf(xv0.x, w0.w, a0.w);
        a0.x = fmaf(xv0.y, w1.x, a0.x); a0.y = fmaf(xv0.y, w1.y, a0.y);
        a0.z = fmaf(xv0.y, w1.z, a0.z); a0.w = fmaf(xv0.y, w1.w, a0.w);
        a0.x = fmaf(xv0.z, w2.x, a0.x); a0.y = fmaf(xv0.z, w2.y, a0.y);
        a0.z = fmaf(xv0.z, w2.z, a0.z); a0.w = fmaf(xv0.z, w2.w, a0.w);
        a0.x = fmaf(xv0.w, w3.x, a0.x); a0.y = fmaf(xv0.w, w3.y, a0.y);
        a0.z = fmaf(xv0.w, w3.z, a0.z); a0.w = fmaf(xv0.w, w3.w, a0.w);
        a1.x = fmaf(xv1.x, w0.x, a1.x); a1.y = fmaf(xv1.x, w0.y, a1.y);
        a1.z = fmaf(xv1.x, w0.z, a1.z); a1.w = fmaf(xv1.x, w0.w, a1.w);
        a1.x = fmaf(xv1.y, w1.x, a1.x); a1.y = fmaf(xv1.y, w1.y, a1.y);
        a1.z = fmaf(xv1.y, w1.z, a1.z); a1.w = fmaf(xv1.y, w1.w, a1.w);
        a1.x = fmaf(xv1.z, w2.x, a1.x); a1.y = fmaf(xv1.z, w2.y, a1.y);
        a1.z = fmaf(xv1.z, w2.z, a1.z); a1.w = fmaf(xv1.z, w2.w, a1.w);
        a1.x = fmaf(xv1.w, w3.x, a1.x); a1.y = fmaf(xv1.w, w3.y, a1.y);
        a1.z = fmaf(xv1.w, w3.z, a1.z); a1.w = fmaf(xv1.w, w3.w, a1.w);
    }
    #pragma unroll
    for (int rr = 0; rr < 2; ++rr) {
        int row = row0 + r0 + rr;
        float4 a = rr ? a1 : a0;
        float sc = (row < n) ? dinv[row] : 0.f;
        __half2 p0 = __floats2half2_rn(a.x * sc, a.y * sc);
        __half2 p1 = __floats2half2_rn(a.z * sc, a.w * sc);
        __half2* dst = (__half2*)&h16[(size_t)row * HID + c0];
        dst[0] = p0;
        dst[1] = p1;
    }
}

extern "C" void kernel_launch(void* const* d_in, const int* in_sizes, int n_in,
                              void* d_out, int out_size, void* d_ws, size_t ws_size,
                              hipStream_t stream) {
    const float* x  = (const float*)d_in[0];
    const int*   ei = (const int*)d_in[1];
    const float* W1 = (const float*)d_in[2];
    const float* b1 = (const float*)d_in[3];
    const float* W2 = (const float*)d_in[4];
    const float* b2 = (const float*)d_in[5];
    float* out = (float*)d_out;

    int n = in_sizes[0] / FIN;      // 100000
    int E = in_sizes[1] / 2;        // 3200000
    const int* src = ei;
    const int* dst = ei + E;

    int nb = (n + BNODES - 1) / BNODES;          // 391 buckets
    int nchunks = (E + CHUNK - 1) / CHUNK;       // 1563 chunks
    int ggrid = (n + G1ROWS) / G1ROWS;           // covers sentinel row n
    int npad = ggrid * G1ROWS;
    int cap = CAPB;

    char* ws = (char*)d_ws;
    size_t off = 0;
    auto alloc = [&](size_t bytes) { char* p = ws + off; off += (bytes + 255) & ~(size_t)255; return p; };
    int*            ec      = (int*)alloc((size_t)nchunks * CHUNK * 4);         // 12.8 MB
    unsigned short* offt    = (unsigned short*)alloc((size_t)nchunks * (nb + 1) * 2); // 1.2 MB
    int*            entries = (int*)alloc((size_t)nb * cap * 4);                // 14.0 MB
    float*          dinv    = (float*)alloc((size_t)n * 4);
    int*            rowbeg  = (int*)alloc((size_t)n * 4);
    int*            rowcnt  = (int*)alloc((size_t)n * 4);
    float*          acc     = (float*)alloc((size_t)n * HID * 4);               // 12.8 MB
    __half*         hh      = (__half*)alloc((size_t)npad * HID * 2);           // 6.4 MB

    // ---- preprocessing: chunk sort (coalesced) -> bucket build (gather) ----
    chunk_sort_kernel<<<nchunks, 256, 0, stream>>>(src, dst, ec, offt, E, nb);
    bucket_build_kernel<<<nb, 1024, 0, stream>>>(ec, offt, entries, dinv, rowbeg, rowcnt,
                                                 n, nb, nchunks, cap);

    // ---- layer 1 ----
    gemm1_kernel<<<ggrid, 256, 0, stream>>>(x, W1, dinv, hh, n);
    gather_kernel<<<(n + 63) / 64, 256, 0, stream>>>(entries, rowbeg, rowcnt, dinv, hh, b1, acc, n, n);

    // ---- layer 2 ----
    gemm2_kernel<<<ggrid, 256, 0, stream>>>(acc, W2, dinv, hh, n);
    gather_kernel<<<(n + 63) / 64, 256, 0, stream>>>(entries, rowbeg, rowcnt, dinv, hh, b2, out, n, n);
}

// Round 11
// 253.193 us; speedup vs baseline: 1.1539x; 1.1539x over previous
//
#include <hip/hip_runtime.h>
#include <hip/hip_fp16.h>

#define FIN 128
#define HID 32
#define BSHIFT 8                 // 256 nodes per coarse bucket
#define BNODES 256
#define CHUNK 2048               // edges per chunk-sort block
#define NBMAX 512                // max coarse buckets supported in LDS
#define CAPB 8960                // max entries per bucket (mean 8184, +8.6 sigma)
#define G1ROWS 64                // rows per gemm block
#define XPAD 4                   // LDS leading-dim pad

// ---------------- A: per-chunk counting sort by bucket (all I/O coalesced) ----------------

__global__ __launch_bounds__(256) void chunk_sort_kernel(const int* __restrict__ src,
                                                         const int* __restrict__ dst,
                                                         int* __restrict__ ec,
                                                         unsigned short* __restrict__ offt,
                                                         int E, int nb) {
    __shared__ int hist[NBMAX];
    __shared__ int pref[NBMAX];
    __shared__ int wsum[128];
    __shared__ int sorted[CHUNK];
    int c = blockIdx.x, t = threadIdx.x;
    int beg = c * CHUNK;
    int cnt = min(CHUNK, E - beg);
    for (int i = t; i < nb; i += 256) hist[i] = 0;
    __syncthreads();
    int bk[8], ent[8];
    #pragma unroll
    for (int j = 0; j < 8; ++j) {
        int i = t + j * 256;
        if (i < cnt) {
            int d = dst[beg + i];
            bk[j]  = ((unsigned)d) >> BSHIFT;
            ent[j] = src[beg + i] | ((d & (BNODES - 1)) << 24);
            atomicAdd(&hist[bk[j]], 1);
        } else bk[j] = -1;
    }
    __syncthreads();
    if (t < 128) {
        int s = 0;
        #pragma unroll
        for (int j = 0; j < 4; ++j) {
            int idx = t * 4 + j;
            int v = (idx < nb) ? hist[idx] : 0;
            pref[idx] = s; s += v;
        }
        wsum[t] = s;
    }
    __syncthreads();
    if (t == 0) { int run = 0; for (int j = 0; j < 128; ++j) { int v = wsum[j]; wsum[j] = run; run += v; } }
    __syncthreads();
    for (int i = t; i < nb; i += 256) { int p = pref[i] + wsum[i >> 2]; pref[i] = p; hist[i] = p; }
    __syncthreads();
    #pragma unroll
    for (int j = 0; j < 8; ++j) {
        if (bk[j] >= 0) {
            int p = atomicAdd(&hist[bk[j]], 1);
            sorted[p] = ent[j];
        }
    }
    __syncthreads();
    for (int i = t; i < cnt; i += 256) ec[(size_t)c * CHUNK + i] = sorted[i];   // coalesced
    unsigned short* row = offt + (size_t)c * (nb + 1);
    for (int i = t; i < nb; i += 256) row[i] = (unsigned short)pref[i];
    if (t == 0) row[nb] = (unsigned short)cnt;
}

// ---------------- B: per-bucket gather of chunk runs + node counting sort ----------------

__global__ __launch_bounds__(1024) void bucket_build_kernel(const int* __restrict__ ec,
                                                            const unsigned short* __restrict__ offt,
                                                            int* __restrict__ entries,
                                                            float* __restrict__ dinv,
                                                            int* __restrict__ rowbeg,
                                                            int* __restrict__ rowcnt,
                                                            int n, int nb, int nchunks, int cap) {
    __shared__ int raw[CAPB];
    __shared__ int srt[CAPB];
    __shared__ int hist[BNODES];
    __shared__ int pref[BNODES];
    __shared__ int cursor[BNODES];
    __shared__ int wsum[64];
    __shared__ int nfill;
    int b = blockIdx.x, t = threadIdx.x;
    if (t < BNODES) hist[t] = 0;
    if (t == 0) nfill = 0;
    __syncthreads();
    for (int c = t; c < nchunks; c += 1024) {
        const unsigned short* row = offt + (size_t)c * (nb + 1);
        int s = row[b], e2 = row[b + 1];
        int m = e2 - s;
        if (m > 0) {
            int base = atomicAdd(&nfill, m);
            const int* p = ec + (size_t)c * CHUNK + s;
            for (int k = 0; k < m; ++k) {
                int e = p[k];
                if (base + k < CAPB) raw[base + k] = e;
                atomicAdd(&hist[((unsigned)e) >> 24], 1);
            }
        }
    }
    __syncthreads();
    int total = min(nfill, CAPB);
    if (t < 64) {
        int s = 0;
        #pragma unroll
        for (int j = 0; j < 4; ++j) { int v = hist[t * 4 + j]; pref[t * 4 + j] = s; s += v; }
        wsum[t] = s;
    }
    __syncthreads();
    if (t == 0) { int run = 0; for (int j = 0; j < 64; ++j) { int v = wsum[j]; wsum[j] = run; run += v; } }
    __syncthreads();
    if (t < BNODES) { int p = pref[t] + wsum[t >> 2]; pref[t] = p; cursor[t] = p; }
    __syncthreads();
    for (int i = t; i < total; i += 1024) {
        int e = raw[i];
        int p = atomicAdd(&cursor[((unsigned)e) >> 24], 1);
        srt[p] = e;
    }
    __syncthreads();
    int* ep = entries + (size_t)b * cap;
    for (int i = t; i < total; i += 1024) ep[i] = srt[i];
    int node = b * BNODES + t;
    if (t < BNODES && node < n) {
        int deg = hist[t];
        dinv[node]   = rsqrtf((float)deg + 1.0f);   // +1 = self-loop
        rowbeg[node] = b * cap + pref[t];
        rowcnt[node] = deg;
    }
}

// ---------------- GEMM1: h16 = (x @ W1) * dinv, register-tiled 2x4, K=128 ----------------

__global__ __launch_bounds__(256) void gemm1_kernel(const float* __restrict__ x,
                                                    const float* __restrict__ W,
                                                    const float* __restrict__ dinv,
                                                    __half* __restrict__ h16, int n) {
    __shared__ float Ws[FIN * HID];              // 16 KB
    __shared__ float xs[G1ROWS][FIN + XPAD];     // 33.8 KB
    int t = threadIdx.x;
    for (int i = t; i < FIN * HID; i += 256) Ws[i] = W[i];
    int row0 = blockIdx.x * G1ROWS;
    for (int idx = t; idx < G1ROWS * (FIN / 4); idx += 256) {
        int r  = idx >> 5;
        int c4 = (idx & 31) * 4;
        int row = row0 + r;
        float4 v = (row < n) ? *(const float4*)&x[(size_t)row * FIN + c4]
                             : make_float4(0.f, 0.f, 0.f, 0.f);
        *(float4*)&xs[r][c4] = v;
    }
    __syncthreads();
    int tr = t >> 3, tc = t & 7;
    int r0 = tr * 2, c0 = tc * 4;
    float4 a0 = make_float4(0.f, 0.f, 0.f, 0.f);
    float4 a1 = make_float4(0.f, 0.f, 0.f, 0.f);
    #pragma unroll 8
    for (int k4 = 0; k4 < FIN / 4; ++k4) {
        float4 xv0 = *(const float4*)&xs[r0][k4 * 4];
        float4 xv1 = *(const float4*)&xs[r0 + 1][k4 * 4];
        float4 w0 = *(const float4*)&Ws[(k4 * 4 + 0) * HID + c0];
        float4 w1 = *(const float4*)&Ws[(k4 * 4 + 1) * HID + c0];
        float4 w2 = *(const float4*)&Ws[(k4 * 4 + 2) * HID + c0];
        float4 w3 = *(const float4*)&Ws[(k4 * 4 + 3) * HID + c0];
        a0.x = fmaf(xv0.x, w0.x, a0.x); a0.y = fmaf(xv0.x, w0.y, a0.y);
        a0.z = fmaf(xv0.x, w0.z, a0.z); a0.w = fmaf(xv0.x, w0.w, a0.w);
        a0.x = fmaf(xv0.y, w1.x, a0.x); a0.y = fmaf(xv0.y, w1.y, a0.y);
        a0.z = fmaf(xv0.y, w1.z, a0.z); a0.w = fmaf(xv0.y, w1.w, a0.w);
        a0.x = fmaf(xv0.z, w2.x, a0.x); a0.y = fmaf(xv0.z, w2.y, a0.y);
        a0.z = fmaf(xv0.z, w2.z, a0.z); a0.w = fmaf(xv0.z, w2.w, a0.w);
        a0.x = fmaf(xv0.w, w3.x, a0.x); a0.y = fmaf(xv0.w, w3.y, a0.y);
        a0.z = fmaf(xv0.w, w3.z, a0.z); a0.w = fmaf(xv0.w, w3.w, a0.w);
        a1.x = fmaf(xv1.x, w0.x, a1.x); a1.y = fmaf(xv1.x, w0.y, a1.y);
        a1.z = fmaf(xv1.x, w0.z, a1.z); a1.w = fmaf(xv1.x, w0.w, a1.w);
        a1.x = fmaf(xv1.y, w1.x, a1.x); a1.y = fmaf(xv1.y, w1.y, a1.y);
        a1.z = fmaf(xv1.y, w1.z, a1.z); a1.w = fmaf(xv1.y, w1.w, a1.w);
        a1.x = fmaf(xv1.z, w2.x, a1.x); a1.y = fmaf(xv1.z, w2.y, a1.y);
        a1.z = fmaf(xv1.z, w2.z, a1.z); a1.w = fmaf(xv1.z, w2.w, a1.w);
        a1.x = fmaf(xv1.w, w3.x, a1.x); a1.y = fmaf(xv1.w, w3.y, a1.y);
        a1.z = fmaf(xv1.w, w3.z, a1.z); a1.w = fmaf(xv1.w, w3.w, a1.w);
    }
    #pragma unroll
    for (int rr = 0; rr < 2; ++rr) {
        int row = row0 + r0 + rr;
        float4 a = rr ? a1 : a0;
        float sc = (row < n) ? dinv[row] : 0.f;
        __half2 p0 = __floats2half2_rn(a.x * sc, a.y * sc);
        __half2 p1 = __floats2half2_rn(a.z * sc, a.w * sc);
        __half2* dst = (__half2*)&h16[(size_t)row * HID + c0];
        dst[0] = p0;
        dst[1] = p1;
    }
}

// ---------------- gather: 16-lane groups, lane owns feature pair, half2 loads ----------------
// out[i] = relu( b + di * (h16[i] + sum_e h16[src]) ). Per edge the group reads one
// contiguous 64-B row (16 lanes x 4 B) -> R9's broadcast line pattern, half the shfls.

__global__ __launch_bounds__(256) void gather_kernel(const int* __restrict__ entries,
                                                     const int* __restrict__ rowbeg,
                                                     const int* __restrict__ rowcnt,
                                                     const float* __restrict__ dinv,
                                                     const __half* __restrict__ h16,
                                                     const float* __restrict__ bias,
                                                     float* __restrict__ out, int n, int sent) {
    int t = threadIdx.x;
    int g = t >> 4, f = t & 15;          // 16 nodes/block; lane owns feats {2f,2f+1}
    int i = blockIdx.x * 16 + g;
    if (i >= n) return;
    float di = dinv[i];
    float s0, s1;
    {   // self term: h*di^2 = h16*di
        __half2 h = *(const __half2*)&h16[(size_t)i * HID + f * 2];
        float2 fp = __half22float2(h);
        s0 = fp.x; s1 = fp.y;
    }
    int beg = rowbeg[i], cnt = rowcnt[i];
    for (int base = 0; base < cnt; base += 16) {
        int idx = beg + base + f;
        int sv = ((base + f) < cnt) ? entries[idx] : sent;  // sentinel = zero row n
        sv &= 0xFFFFFF;                                     // strip dlocal once per 16 edges
        #pragma unroll
        for (int j0 = 0; j0 < 16; j0 += 8) {
            __half2 hv[8];
            #pragma unroll
            for (int j = 0; j < 8; ++j) {
                int e = __shfl(sv, j0 + j, 16);
                hv[j] = *(const __half2*)&h16[(size_t)e * HID + f * 2];  // 8 loads in flight
            }
            #pragma unroll
            for (int j = 0; j < 8; ++j) {
                s0 += __half2float(__low2half(hv[j]));    // fusable to v_fma_mix
                s1 += __half2float(__high2half(hv[j]));
            }
        }
    }
    float2 b2 = *(const float2*)&bias[f * 2];
    float2 o;
    o.x = fmaxf(b2.x + di * s0, 0.f);
    o.y = fmaxf(b2.y + di * s1, 0.f);
    *(float2*)&out[(size_t)i * HID + f * 2] = o;
}

// ---------------- GEMM2: h16 = (hin @ W2) * dinv, register-tiled 2x4, K=32 ----------------

__global__ __launch_bounds__(256) void gemm2_kernel(const float* __restrict__ hin,
                                                    const float* __restrict__ W,
                                                    const float* __restrict__ dinv,
                                                    __half* __restrict__ h16, int n) {
    __shared__ float Ws[HID * HID];              // 4 KB
    __shared__ float hs[G1ROWS][HID + XPAD];     // 9 KB
    int t = threadIdx.x;
    for (int i = t; i < HID * HID; i += 256) Ws[i] = W[i];
    int row0 = blockIdx.x * G1ROWS;
    for (int idx = t; idx < G1ROWS * (HID / 4); idx += 256) {
        int r  = idx >> 3;
        int c4 = (idx & 7) * 4;
        int row = row0 + r;
        float4 v = (row < n) ? *(const float4*)&hin[(size_t)row * HID + c4]
                             : make_float4(0.f, 0.f, 0.f, 0.f);
        *(float4*)&hs[r][c4] = v;
    }
    __syncthreads();
    int tr = t >> 3, tc = t & 7;
    int r0 = tr * 2, c0 = tc * 4;
    float4 a0 = make_float4(0.f, 0.f, 0.f, 0.f);
    float4 a1 = make_float4(0.f, 0.f, 0.f, 0.f);
    #pragma unroll
    for (int k4 = 0; k4 < HID / 4; ++k4) {
        float4 xv0 = *(const float4*)&hs[r0][k4 * 4];
        float4 xv1 = *(const float4*)&hs[r0 + 1][k4 * 4];
        float4 w0 = *(const float4*)&Ws[(k4 * 4 + 0) * HID + c0];
        float4 w1 = *(const float4*)&Ws[(k4 * 4 + 1) * HID + c0];
        float4 w2 = *(const float4*)&Ws[(k4 * 4 + 2) * HID + c0];
        float4 w3 = *(const float4*)&Ws[(k4 * 4 + 3) * HID + c0];
        a0.x = fmaf(xv0.x, w0.x, a0.x); a0.y = fmaf(xv0.x, w0.y, a0.y);
        a0.z = fmaf(xv0.x, w0.z, a0.z); a0.w = fmaf(xv0.x, w0.w, a0.w);
        a0.x = fmaf(xv0.y, w1.x, a0.x); a0.y = fmaf(xv0.y, w1.y, a0.y);
        a0.z = fmaf(xv0.y, w1.z, a0.z); a0.w = fmaf(xv0.y, w1.w, a0.w);
        a0.x = fmaf(xv0.z, w2.x, a0.x); a0.y = fmaf(xv0.z, w2.y, a0.y);
        a0.z = fmaf(xv0.z, w2.z, a0.z); a0.w = fmaf(xv0.z, w2.w, a0.w);
        a0.x = fmaf(xv0.w, w3.x, a0.x); a0.y = fmaf(xv0.w, w3.y, a0.y);
        a0.z = fmaf(xv0.w, w3.z, a0.z); a0.w = fmaf(xv0.w, w3.w, a0.w);
        a1.x = fmaf(xv1.x, w0.x, a1.x); a1.y = fmaf(xv1.x, w0.y, a1.y);
        a1.z = fmaf(xv1.x, w0.z, a1.z); a1.w = fmaf(xv1.x, w0.w, a1.w);
        a1.x = fmaf(xv1.y, w1.x, a1.x); a1.y = fmaf(xv1.y, w1.y, a1.y);
        a1.z = fmaf(xv1.y, w1.z, a1.z); a1.w = fmaf(xv1.y, w1.w, a1.w);
        a1.x = fmaf(xv1.z, w2.x, a1.x); a1.y = fmaf(xv1.z, w2.y, a1.y);
        a1.z = fmaf(xv1.z, w2.z, a1.z); a1.w = fmaf(xv1.z, w2.w, a1.w);
        a1.x = fmaf(xv1.w, w3.x, a1.x); a1.y = fmaf(xv1.w, w3.y, a1.y);
        a1.z = fmaf(xv1.w, w3.z, a1.z); a1.w = fmaf(xv1.w, w3.w, a1.w);
    }
    #pragma unroll
    for (int rr = 0; rr < 2; ++rr) {
        int row = row0 + r0 + rr;
        float4 a = rr ? a1 : a0;
        float sc = (row < n) ? dinv[row] : 0.f;
        __half2 p0 = __floats2half2_rn(a.x * sc, a.y * sc);
        __half2 p1 = __floats2half2_rn(a.z * sc, a.w * sc);
        __half2* dst = (__half2*)&h16[(size_t)row * HID + c0];
        dst[0] = p0;
        dst[1] = p1;
    }
}

extern "C" void kernel_launch(void* const* d_in, const int* in_sizes, int n_in,
                              void* d_out, int out_size, void* d_ws, size_t ws_size,
                              hipStream_t stream) {
    const float* x  = (const float*)d_in[0];
    const int*   ei = (const int*)d_in[1];
    const float* W1 = (const float*)d_in[2];
    const float* b1 = (const float*)d_in[3];
    const float* W2 = (const float*)d_in[4];
    const float* b2 = (const float*)d_in[5];
    float* out = (float*)d_out;

    int n = in_sizes[0] / FIN;      // 100000
    int E = in_sizes[1] / 2;        // 3200000
    const int* src = ei;
    const int* dst = ei + E;

    int nb = (n + BNODES - 1) / BNODES;          // 391 buckets
    int nchunks = (E + CHUNK - 1) / CHUNK;       // 1563 chunks
    int ggrid = (n + G1ROWS) / G1ROWS;           // covers sentinel row n
    int npad = ggrid * G1ROWS;
    int cap = CAPB;

    char* ws = (char*)d_ws;
    size_t off = 0;
    auto alloc = [&](size_t bytes) { char* p = ws + off; off += (bytes + 255) & ~(size_t)255; return p; };
    int*            ec      = (int*)alloc((size_t)nchunks * CHUNK * 4);         // 12.8 MB
    unsigned short* offt    = (unsigned short*)alloc((size_t)nchunks * (nb + 1) * 2); // 1.2 MB
    int*            entries = (int*)alloc((size_t)nb * cap * 4);                // 14.0 MB
    float*          dinv    = (float*)alloc((size_t)n * 4);
    int*            rowbeg  = (int*)alloc((size_t)n * 4);
    int*            rowcnt  = (int*)alloc((size_t)n * 4);
    float*          acc     = (float*)alloc((size_t)n * HID * 4);               // 12.8 MB
    __half*         hh      = (__half*)alloc((size_t)npad * HID * 2);           // 6.4 MB

    // ---- preprocessing: chunk sort (coalesced) -> bucket build (gather) ----
    chunk_sort_kernel<<<nchunks, 256, 0, stream>>>(src, dst, ec, offt, E, nb);
    bucket_build_kernel<<<nb, 1024, 0, stream>>>(ec, offt, entries, dinv, rowbeg, rowcnt,
                                                 n, nb, nchunks, cap);

    // ---- layer 1 ----
    gemm1_kernel<<<ggrid, 256, 0, stream>>>(x, W1, dinv, hh, n);
    gather_kernel<<<(n + 15) / 16, 256, 0, stream>>>(entries, rowbeg, rowcnt, dinv, hh, b1, acc, n, n);

    // ---- layer 2 ----
    gemm2_kernel<<<ggrid, 256, 0, stream>>>(acc, W2, dinv, hh, n);
    gather_kernel<<<(n + 15) / 16, 256, 0, stream>>>(entries, rowbeg, rowcnt, dinv, hh, b2, out, n, n);
}

// Round 12
// 251.574 us; speedup vs baseline: 1.1613x; 1.0064x over previous
//
#include <hip/hip_runtime.h>
#include <hip/hip_fp16.h>

#define FIN 128
#define HID 32
#define BSHIFT 8                 // 256 nodes per coarse bucket
#define BNODES 256
#define CHUNK 2048               // edges per chunk-sort block
#define NBMAX 512                // max coarse buckets supported in LDS
#define CAPB 8960                // max entries per bucket (mean 8184, +8.6 sigma)
#define G1ROWS 64                // rows per gemm block
#define XPAD 4                   // LDS leading-dim pad

// ---------------- A: per-chunk counting sort by bucket (all I/O coalesced) ----------------

__global__ __launch_bounds__(256) void chunk_sort_kernel(const int* __restrict__ src,
                                                         const int* __restrict__ dst,
                                                         int* __restrict__ ec,
                                                         unsigned short* __restrict__ offt,
                                                         int E, int nb) {
    __shared__ int hist[NBMAX];
    __shared__ int pref[NBMAX];
    __shared__ int wsum[128];
    __shared__ int sorted[CHUNK];
    int c = blockIdx.x, t = threadIdx.x;
    int beg = c * CHUNK;
    int cnt = min(CHUNK, E - beg);
    for (int i = t; i < nb; i += 256) hist[i] = 0;
    __syncthreads();
    int bk[8], ent[8];
    #pragma unroll
    for (int j = 0; j < 8; ++j) {
        int i = t + j * 256;
        if (i < cnt) {
            int d = dst[beg + i];
            bk[j]  = ((unsigned)d) >> BSHIFT;
            ent[j] = src[beg + i] | ((d & (BNODES - 1)) << 24);
            atomicAdd(&hist[bk[j]], 1);
        } else bk[j] = -1;
    }
    __syncthreads();
    if (t < 128) {
        int s = 0;
        #pragma unroll
        for (int j = 0; j < 4; ++j) {
            int idx = t * 4 + j;
            int v = (idx < nb) ? hist[idx] : 0;
            pref[idx] = s; s += v;
        }
        wsum[t] = s;
    }
    __syncthreads();
    if (t == 0) { int run = 0; for (int j = 0; j < 128; ++j) { int v = wsum[j]; wsum[j] = run; run += v; } }
    __syncthreads();
    for (int i = t; i < nb; i += 256) { int p = pref[i] + wsum[i >> 2]; pref[i] = p; hist[i] = p; }
    __syncthreads();
    #pragma unroll
    for (int j = 0; j < 8; ++j) {
        if (bk[j] >= 0) {
            int p = atomicAdd(&hist[bk[j]], 1);
            sorted[p] = ent[j];
        }
    }
    __syncthreads();
    for (int i = t; i < cnt; i += 256) ec[(size_t)c * CHUNK + i] = sorted[i];   // coalesced
    unsigned short* row = offt + (size_t)c * (nb + 1);
    for (int i = t; i < nb; i += 256) row[i] = (unsigned short)pref[i];
    if (t == 0) row[nb] = (unsigned short)cnt;
}

// ---------------- B: per-bucket gather of chunk runs + node counting sort ----------------

__global__ __launch_bounds__(1024) void bucket_build_kernel(const int* __restrict__ ec,
                                                            const unsigned short* __restrict__ offt,
                                                            int* __restrict__ entries,
                                                            float* __restrict__ dinv,
                                                            int* __restrict__ rowbeg,
                                                            int* __restrict__ rowcnt,
                                                            int n, int nb, int nchunks, int cap) {
    __shared__ int raw[CAPB];
    __shared__ int srt[CAPB];
    __shared__ int hist[BNODES];
    __shared__ int pref[BNODES];
    __shared__ int cursor[BNODES];
    __shared__ int wsum[64];
    __shared__ int nfill;
    int b = blockIdx.x, t = threadIdx.x;
    if (t < BNODES) hist[t] = 0;
    if (t == 0) nfill = 0;
    __syncthreads();
    for (int c = t; c < nchunks; c += 1024) {
        const unsigned short* row = offt + (size_t)c * (nb + 1);
        int s = row[b], e2 = row[b + 1];
        int m = e2 - s;
        if (m > 0) {
            int base = atomicAdd(&nfill, m);
            const int* p = ec + (size_t)c * CHUNK + s;
            for (int k = 0; k < m; ++k) {
                int e = p[k];
                if (base + k < CAPB) raw[base + k] = e;
                atomicAdd(&hist[((unsigned)e) >> 24], 1);
            }
        }
    }
    __syncthreads();
    int total = min(nfill, CAPB);
    if (t < 64) {
        int s = 0;
        #pragma unroll
        for (int j = 0; j < 4; ++j) { int v = hist[t * 4 + j]; pref[t * 4 + j] = s; s += v; }
        wsum[t] = s;
    }
    __syncthreads();
    if (t == 0) { int run = 0; for (int j = 0; j < 64; ++j) { int v = wsum[j]; wsum[j] = run; run += v; } }
    __syncthreads();
    if (t < BNODES) { int p = pref[t] + wsum[t >> 2]; pref[t] = p; cursor[t] = p; }
    __syncthreads();
    for (int i = t; i < total; i += 1024) {
        int e = raw[i];
        int p = atomicAdd(&cursor[((unsigned)e) >> 24], 1);
        srt[p] = e;
    }
    __syncthreads();
    int* ep = entries + (size_t)b * cap;
    for (int i = t; i < total; i += 1024) ep[i] = srt[i];
    int node = b * BNODES + t;
    if (t < BNODES && node < n) {
        int deg = hist[t];
        dinv[node]   = rsqrtf((float)deg + 1.0f);   // +1 = self-loop
        rowbeg[node] = b * cap + pref[t];
        rowcnt[node] = deg;
    }
}

// ---------------- GEMM1: h16 = (x @ W1) * dinv; x read direct from global ----------------
// W staged in LDS (16 KB only -> high occupancy); each thread owns 2 rows x 4 cols.
// x row chunks are read sequentially per thread (L1/L3-served after first touch).

__global__ __launch_bounds__(256) void gemm1_kernel(const float* __restrict__ x,
                                                    const float* __restrict__ W,
                                                    const float* __restrict__ dinv,
                                                    __half* __restrict__ h16, int n) {
    __shared__ float Ws[FIN * HID];              // 16 KB
    int t = threadIdx.x;
    for (int i = t; i < FIN * HID; i += 256) Ws[i] = W[i];
    __syncthreads();
    int row0 = blockIdx.x * G1ROWS;
    int tr = t >> 3, tc = t & 7;
    int r0 = row0 + tr * 2, c0 = tc * 4;
    bool v0 = r0 < n, v1 = (r0 + 1) < n;
    const float* p0 = v0 ? &x[(size_t)r0 * FIN] : x;        // safe dummy row
    const float* p1 = v1 ? &x[(size_t)(r0 + 1) * FIN] : x;
    float4 a0 = make_float4(0.f, 0.f, 0.f, 0.f);
    float4 a1 = make_float4(0.f, 0.f, 0.f, 0.f);
    #pragma unroll 8
    for (int k4 = 0; k4 < FIN / 4; ++k4) {
        float4 xv0 = *(const float4*)&p0[k4 * 4];
        float4 xv1 = *(const float4*)&p1[k4 * 4];
        float4 w0 = *(const float4*)&Ws[(k4 * 4 + 0) * HID + c0];
        float4 w1 = *(const float4*)&Ws[(k4 * 4 + 1) * HID + c0];
        float4 w2 = *(const float4*)&Ws[(k4 * 4 + 2) * HID + c0];
        float4 w3 = *(const float4*)&Ws[(k4 * 4 + 3) * HID + c0];
        a0.x = fmaf(xv0.x, w0.x, a0.x); a0.y = fmaf(xv0.x, w0.y, a0.y);
        a0.z = fmaf(xv0.x, w0.z, a0.z); a0.w = fmaf(xv0.x, w0.w, a0.w);
        a0.x = fmaf(xv0.y, w1.x, a0.x); a0.y = fmaf(xv0.y, w1.y, a0.y);
        a0.z = fmaf(xv0.y, w1.z, a0.z); a0.w = fmaf(xv0.y, w1.w, a0.w);
        a0.x = fmaf(xv0.z, w2.x, a0.x); a0.y = fmaf(xv0.z, w2.y, a0.y);
        a0.z = fmaf(xv0.z, w2.z, a0.z); a0.w = fmaf(xv0.z, w2.w, a0.w);
        a0.x = fmaf(xv0.w, w3.x, a0.x); a0.y = fmaf(xv0.w, w3.y, a0.y);
        a0.z = fmaf(xv0.w, w3.z, a0.z); a0.w = fmaf(xv0.w, w3.w, a0.w);
        a1.x = fmaf(xv1.x, w0.x, a1.x); a1.y = fmaf(xv1.x, w0.y, a1.y);
        a1.z = fmaf(xv1.x, w0.z, a1.z); a1.w = fmaf(xv1.x, w0.w, a1.w);
        a1.x = fmaf(xv1.y, w1.x, a1.x); a1.y = fmaf(xv1.y, w1.y, a1.y);
        a1.z = fmaf(xv1.y, w1.z, a1.z); a1.w = fmaf(xv1.y, w1.w, a1.w);
        a1.x = fmaf(xv1.z, w2.x, a1.x); a1.y = fmaf(xv1.z, w2.y, a1.y);
        a1.z = fmaf(xv1.z, w2.z, a1.z); a1.w = fmaf(xv1.z, w2.w, a1.w);
        a1.x = fmaf(xv1.w, w3.x, a1.x); a1.y = fmaf(xv1.w, w3.y, a1.y);
        a1.z = fmaf(xv1.w, w3.z, a1.z); a1.w = fmaf(xv1.w, w3.w, a1.w);
    }
    #pragma unroll
    for (int rr = 0; rr < 2; ++rr) {
        int row = r0 + rr;
        float4 a = rr ? a1 : a0;
        float sc = (row < n) ? dinv[row] : 0.f;
        __half2 q0 = __floats2half2_rn(a.x * sc, a.y * sc);
        __half2 q1 = __floats2half2_rn(a.z * sc, a.w * sc);
        __half2* dstp = (__half2*)&h16[(size_t)row * HID + c0];
        dstp[0] = q0;
        dstp[1] = q1;
    }
}

// ---------------- gather: 16-lane groups, lane owns feature pair, half2 loads ----------------

__global__ __launch_bounds__(256) void gather_kernel(const int* __restrict__ entries,
                                                     const int* __restrict__ rowbeg,
                                                     const int* __restrict__ rowcnt,
                                                     const float* __restrict__ dinv,
                                                     const __half* __restrict__ h16,
                                                     const float* __restrict__ bias,
                                                     float* __restrict__ out, int n, int sent) {
    int t = threadIdx.x;
    int g = t >> 4, f = t & 15;          // 16 nodes/block; lane owns feats {2f,2f+1}
    int i = blockIdx.x * 16 + g;
    if (i >= n) return;
    float di = dinv[i];
    float s0, s1;
    {   // self term: h*di^2 = h16*di
        __half2 h = *(const __half2*)&h16[(size_t)i * HID + f * 2];
        float2 fp = __half22float2(h);
        s0 = fp.x; s1 = fp.y;
    }
    int beg = rowbeg[i], cnt = rowcnt[i];
    for (int base = 0; base < cnt; base += 16) {
        int idx = beg + base + f;
        int sv = ((base + f) < cnt) ? entries[idx] : sent;  // sentinel = zero row n
        sv &= 0xFFFFFF;
        #pragma unroll
        for (int j0 = 0; j0 < 16; j0 += 8) {
            __half2 hv[8];
            #pragma unroll
            for (int j = 0; j < 8; ++j) {
                int e = __shfl(sv, j0 + j, 16);
                hv[j] = *(const __half2*)&h16[(size_t)e * HID + f * 2];  // 8 loads in flight
            }
            #pragma unroll
            for (int j = 0; j < 8; ++j) {
                s0 += __half2float(__low2half(hv[j]));
                s1 += __half2float(__high2half(hv[j]));
            }
        }
    }
    float2 b2 = *(const float2*)&bias[f * 2];
    float2 o;
    o.x = fmaxf(b2.x + di * s0, 0.f);
    o.y = fmaxf(b2.y + di * s1, 0.f);
    *(float2*)&out[(size_t)i * HID + f * 2] = o;
}

// ---------------- GEMM2: h16 = (hin @ W2) * dinv, register-tiled 2x4, K=32 ----------------

__global__ __launch_bounds__(256) void gemm2_kernel(const float* __restrict__ hin,
                                                    const float* __restrict__ W,
                                                    const float* __restrict__ dinv,
                                                    __half* __restrict__ h16, int n) {
    __shared__ float Ws[HID * HID];              // 4 KB
    __shared__ float hs[G1ROWS][HID + XPAD];     // 9 KB
    int t = threadIdx.x;
    for (int i = t; i < HID * HID; i += 256) Ws[i] = W[i];
    int row0 = blockIdx.x * G1ROWS;
    for (int idx = t; idx < G1ROWS * (HID / 4); idx += 256) {
        int r  = idx >> 3;
        int c4 = (idx & 7) * 4;
        int row = row0 + r;
        float4 v = (row < n) ? *(const float4*)&hin[(size_t)row * HID + c4]
                             : make_float4(0.f, 0.f, 0.f, 0.f);
        *(float4*)&hs[r][c4] = v;
    }
    __syncthreads();
    int tr = t >> 3, tc = t & 7;
    int r0 = tr * 2, c0 = tc * 4;
    float4 a0 = make_float4(0.f, 0.f, 0.f, 0.f);
    float4 a1 = make_float4(0.f, 0.f, 0.f, 0.f);
    #pragma unroll
    for (int k4 = 0; k4 < HID / 4; ++k4) {
        float4 xv0 = *(const float4*)&hs[r0][k4 * 4];
        float4 xv1 = *(const float4*)&hs[r0 + 1][k4 * 4];
        float4 w0 = *(const float4*)&Ws[(k4 * 4 + 0) * HID + c0];
        float4 w1 = *(const float4*)&Ws[(k4 * 4 + 1) * HID + c0];
        float4 w2 = *(const float4*)&Ws[(k4 * 4 + 2) * HID + c0];
        float4 w3 = *(const float4*)&Ws[(k4 * 4 + 3) * HID + c0];
        a0.x = fmaf(xv0.x, w0.x, a0.x); a0.y = fmaf(xv0.x, w0.y, a0.y);
        a0.z = fmaf(xv0.x, w0.z, a0.z); a0.w = fmaf(xv0.x, w0.w, a0.w);
        a0.x = fmaf(xv0.y, w1.x, a0.x); a0.y = fmaf(xv0.y, w1.y, a0.y);
        a0.z = fmaf(xv0.y, w1.z, a0.z); a0.w = fmaf(xv0.y, w1.w, a0.w);
        a0.x = fmaf(xv0.z, w2.x, a0.x); a0.y = fmaf(xv0.z, w2.y, a0.y);
        a0.z = fmaf(xv0.z, w2.z, a0.z); a0.w = fmaf(xv0.z, w2.w, a0.w);
        a0.x = fmaf(xv0.w, w3.x, a0.x); a0.y = fmaf(xv0.w, w3.y, a0.y);
        a0.z = fmaf(xv0.w, w3.z, a0.z); a0.w = fmaf(xv0.w, w3.w, a0.w);
        a1.x = fmaf(xv1.x, w0.x, a1.x); a1.y = fmaf(xv1.x, w0.y, a1.y);
        a1.z = fmaf(xv1.x, w0.z, a1.z); a1.w = fmaf(xv1.x, w0.w, a1.w);
        a1.x = fmaf(xv1.y, w1.x, a1.x); a1.y = fmaf(xv1.y, w1.y, a1.y);
        a1.z = fmaf(xv1.y, w1.z, a1.z); a1.w = fmaf(xv1.y, w1.w, a1.w);
        a1.x = fmaf(xv1.z, w2.x, a1.x); a1.y = fmaf(xv1.z, w2.y, a1.y);
        a1.z = fmaf(xv1.z, w2.z, a1.z); a1.w = fmaf(xv1.z, w2.w, a1.w);
        a1.x = fmaf(xv1.w, w3.x, a1.x); a1.y = fmaf(xv1.w, w3.y, a1.y);
        a1.z = fmaf(xv1.w, w3.z, a1.z); a1.w = fmaf(xv1.w, w3.w, a1.w);
    }
    #pragma unroll
    for (int rr = 0; rr < 2; ++rr) {
        int row = row0 + r0 + rr;
        float4 a = rr ? a1 : a0;
        float sc = (row < n) ? dinv[row] : 0.f;
        __half2 q0 = __floats2half2_rn(a.x * sc, a.y * sc);
        __half2 q1 = __floats2half2_rn(a.z * sc, a.w * sc);
        __half2* dstp = (__half2*)&h16[(size_t)row * HID + c0];
        dstp[0] = q0;
        dstp[1] = q1;
    }
}

extern "C" void kernel_launch(void* const* d_in, const int* in_sizes, int n_in,
                              void* d_out, int out_size, void* d_ws, size_t ws_size,
                              hipStream_t stream) {
    const float* x  = (const float*)d_in[0];
    const int*   ei = (const int*)d_in[1];
    const float* W1 = (const float*)d_in[2];
    const float* b1 = (const float*)d_in[3];
    const float* W2 = (const float*)d_in[4];
    const float* b2 = (const float*)d_in[5];
    float* out = (float*)d_out;

    int n = in_sizes[0] / FIN;      // 100000
    int E = in_sizes[1] / 2;        // 3200000
    const int* src = ei;
    const int* dst = ei + E;

    int nb = (n + BNODES - 1) / BNODES;          // 391 buckets
    int nchunks = (E + CHUNK - 1) / CHUNK;       // 1563 chunks
    int ggrid = (n + G1ROWS) / G1ROWS;           // covers sentinel row n
    int npad = ggrid * G1ROWS;
    int cap = CAPB;

    char* ws = (char*)d_ws;
    size_t off = 0;
    auto alloc = [&](size_t bytes) { char* p = ws + off; off += (bytes + 255) & ~(size_t)255; return p; };
    int*            ec      = (int*)alloc((size_t)nchunks * CHUNK * 4);         // 12.8 MB
    unsigned short* offt    = (unsigned short*)alloc((size_t)nchunks * (nb + 1) * 2); // 1.2 MB
    int*            entries = (int*)alloc((size_t)nb * cap * 4);                // 14.0 MB
    float*          dinv    = (float*)alloc((size_t)n * 4);
    int*            rowbeg  = (int*)alloc((size_t)n * 4);
    int*            rowcnt  = (int*)alloc((size_t)n * 4);
    float*          acc     = (float*)alloc((size_t)n * HID * 4);               // 12.8 MB
    __half*         hh      = (__half*)alloc((size_t)npad * HID * 2);           // 6.4 MB

    // ---- preprocessing: chunk sort (coalesced) -> bucket build (gather) ----
    chunk_sort_kernel<<<nchunks, 256, 0, stream>>>(src, dst, ec, offt, E, nb);
    bucket_build_kernel<<<nb, 1024, 0, stream>>>(ec, offt, entries, dinv, rowbeg, rowcnt,
                                                 n, nb, nchunks, cap);

    // ---- layer 1 ----
    gemm1_kernel<<<ggrid, 256, 0, stream>>>(x, W1, dinv, hh, n);
    gather_kernel<<<(n + 15) / 16, 256, 0, stream>>>(entries, rowbeg, rowcnt, dinv, hh, b1, acc, n, n);

    // ---- layer 2 ----
    gemm2_kernel<<<ggrid, 256, 0, stream>>>(acc, W2, dinv, hh, n);
    gather_kernel<<<(n + 15) / 16, 256, 0, stream>>>(entries, rowbeg, rowcnt, dinv, hh, b2, out, n, n);
}